// Round 15
// baseline (12478.584 us; speedup 1.0000x reference)
//
#include <hip/hip_runtime.h>
#include <math.h>

#define B 512
#define S 256
#define D 64
#define H 512

// workspace layout (floats)
#define HBUF_OFF 0            // 2 slots of B*H
#define CBUF_OFF (2*B*H)      // 2 slots of B*H
#define XATT_OFF (4*B*H)      // B*D

__global__ __launch_bounds__(256) void init_zero(float* __restrict__ ws) {
    int i = blockIdx.x * blockDim.x + threadIdx.x;
    if (i < B*H) {
        ws[HBUF_OFF + i] = 0.f;   // h slot 0
        ws[CBUF_OFF + i] = 0.f;   // c slot 0
    }
}

// One WG per 2 rows. threads: d = tid&63, r = (tid>>6)&1, p = tid>>7 (k-split)
__global__ __launch_bounds__(256) void attn_kernel(
    const float* __restrict__ x, const float* __restrict__ Wa,
    const float* __restrict__ Ua, const float* __restrict__ ba,
    const float* __restrict__ Va, float* __restrict__ ws, int t)
{
    const int d = threadIdx.x & 63;
    const int r = (threadIdx.x >> 6) & 1;
    const int p = threadIdx.x >> 7;
    const int b = blockIdx.x * 2 + r;

    const int rd = t & 1;
    const float* __restrict__ hrow = ws + HBUF_OFF + rd*B*H + b*H;
    const float* __restrict__ crow = ws + CBUF_OFF + rd*B*H + b*H;
    const float* __restrict__ xrow = x + ((size_t)b*S + t)*D;

    __shared__ float part[2][2][64];
    __shared__ float ta[2][64];
    __shared__ float pv[2][2][64];

    float a = 0.f;
    if (p == 0) {
        a = ba[d];
        #pragma unroll 8
        for (int k = 0; k < D; ++k) a += xrow[k] * Wa[k*D + d];
        #pragma unroll 8
        for (int k = 0; k < H; ++k) a += hrow[k] * Ua[k*D + d];
    } else {
        #pragma unroll 8
        for (int k = 0; k < H; ++k) a += crow[k] * Ua[(H + k)*D + d];
    }
    part[r][p][d] = a;
    __syncthreads();
    if (p == 0) {
        ta[r][d] = tanhf(part[r][0][d] + part[r][1][d]);
    }
    __syncthreads();
    float av = 0.f;
    {
        const int k0 = p * 32;
        #pragma unroll 8
        for (int k = k0; k < k0 + 32; ++k) av += ta[r][k] * Va[k*D + d];
    }
    pv[r][p][d] = av;
    __syncthreads();
    float v = pv[r][0][d] + pv[r][1][d];
    // softmax over 64 lanes (one wave per (r,p))
    float m = v;
    #pragma unroll
    for (int o = 32; o > 0; o >>= 1) m = fmaxf(m, __shfl_xor(m, o));
    float e = expf(v - m);
    float ssum = e;
    #pragma unroll
    for (int o = 32; o > 0; o >>= 1) ssum += __shfl_xor(ssum, o);
    float alpha = e / ssum;
    if (p == 0) {
        ws[XATT_OFF + b*D + d] = alpha * xrow[d];
    }
}

// Gate GEMM + state update.
// grid (16,16): blockIdx.x = unit tile (32 units), blockIdx.y = row tile (32 rows)
// 256 threads: tm = tid&7 (row group), tn = tid>>3 (unit 0..31)
// thread computes rows {tm, tm+8, tm+16, tm+24} x unit u0+tn x 4 gates
__global__ __launch_bounds__(256) void gates_kernel(
    const float* __restrict__ Wih, const float* __restrict__ Whh,
    const float* __restrict__ bih, const float* __restrict__ bhh,
    float* __restrict__ ws, int t)
{
    const int tm = threadIdx.x & 7;
    const int tn = threadIdx.x >> 3;
    const int u0 = blockIdx.x * 32;
    const int r0 = blockIdx.y * 32;
    const int u  = u0 + tn;

    __shared__ float h_lds[32][68];      // 68 = 64 + 4 pad (17 quads, odd -> conflict-free)
    __shared__ float w_lds[4][32][68];

    const int rd = t & 1, wr = rd ^ 1;
    const float* __restrict__ hbuf_r = ws + HBUF_OFF + rd*B*H;
    const float* __restrict__ cbuf_r = ws + CBUF_OFF + rd*B*H;
    float* __restrict__ hbuf_w = ws + HBUF_OFF + wr*B*H;
    float* __restrict__ cbuf_w = ws + CBUF_OFF + wr*B*H;
    const float* __restrict__ xatt = ws + XATT_OFF;

    float acc[4][4];
    #pragma unroll
    for (int i = 0; i < 4; ++i)
        #pragma unroll
        for (int q = 0; q < 4; ++q) acc[i][q] = 0.f;

    // 8 k-blocks over (h, W_hh), then 1 block over (x_att, W_ih)
    for (int kb = 0; kb < 9; ++kb) {
        __syncthreads();
        {
            const float* src; int ldsrc, kofs;
            if (kb < 8) { src = Whh; ldsrc = H; kofs = kb*64; }
            else        { src = Wih; ldsrc = D; kofs = 0; }
            // stage W block: 128 rows x 16 float4
            #pragma unroll
            for (int it = 0; it < 8; ++it) {
                int j = threadIdx.x + it*256;
                int f4c = j & 15, row = j >> 4;       // row 0..127
                int uu = row & 31, q = row >> 5;
                float4 v = *reinterpret_cast<const float4*>(src + (size_t)(q*H + u0 + uu)*ldsrc + kofs + f4c*4);
                *reinterpret_cast<float4*>(&w_lds[q][uu][f4c*4]) = v;
            }
            // stage activation block: 32 rows x 16 float4
            const float* hsrc = (kb < 8) ? hbuf_r : xatt;
            int ldh  = (kb < 8) ? H : D;
            int kofs2 = (kb < 8) ? kb*64 : 0;
            #pragma unroll
            for (int it = 0; it < 2; ++it) {
                int j = threadIdx.x + it*256;
                int f4c = j & 15, rl = j >> 4;        // rl 0..31
                float4 v = *reinterpret_cast<const float4*>(hsrc + (size_t)(r0 + rl)*ldh + kofs2 + f4c*4);
                *reinterpret_cast<float4*>(&h_lds[rl][f4c*4]) = v;
            }
        }
        __syncthreads();
        #pragma unroll
        for (int k4 = 0; k4 < 16; ++k4) {
            float4 wv[4], hv[4];
            #pragma unroll
            for (int q = 0; q < 4; ++q)
                wv[q] = *reinterpret_cast<const float4*>(&w_lds[q][tn][k4*4]);
            #pragma unroll
            for (int i = 0; i < 4; ++i)
                hv[i] = *reinterpret_cast<const float4*>(&h_lds[tm + 8*i][k4*4]);
            #pragma unroll
            for (int i = 0; i < 4; ++i)
                #pragma unroll
                for (int q = 0; q < 4; ++q) {
                    acc[i][q] += hv[i].x * wv[q].x;
                    acc[i][q] += hv[i].y * wv[q].y;
                    acc[i][q] += hv[i].z * wv[q].z;
                    acc[i][q] += hv[i].w * wv[q].w;
                }
        }
    }

    float bsum[4];
    #pragma unroll
    for (int q = 0; q < 4; ++q) bsum[q] = bih[q*H + u] + bhh[q*H + u];

    #pragma unroll
    for (int i = 0; i < 4; ++i) {
        int b = r0 + tm + 8*i;
        float gi = acc[i][0] + bsum[0];
        float gf = acc[i][1] + bsum[1];
        float gg = acc[i][2] + bsum[2];
        float go = acc[i][3] + bsum[3];
        float c_old = cbuf_r[(size_t)b*H + u];
        float si = 1.f / (1.f + expf(-gi));
        float sf = 1.f / (1.f + expf(-gf));
        float so = 1.f / (1.f + expf(-go));
        float cn = sf * c_old + si * tanhf(gg);
        float hn = so * tanhf(cn);
        cbuf_w[(size_t)b*H + u] = cn;
        hbuf_w[(size_t)b*H + u] = hn;
    }
}

// y[b][j] = h_T[b] . fc_w[j] + fc_b[j]
__global__ __launch_bounds__(256) void fc_kernel(
    const float* __restrict__ fcw, const float* __restrict__ fcb,
    const float* __restrict__ ws, float* __restrict__ out)
{
    const int b = blockIdx.x;
    __shared__ float hrow[H];
    const float* __restrict__ hp = ws + HBUF_OFF + 0*B*H + (size_t)b*H;  // final h in slot 0 (S even)
    for (int k = threadIdx.x; k < H; k += 256) hrow[k] = hp[k];
    __syncthreads();
    int j = threadIdx.x;
    if (j < 24) {
        float a = fcb[j];
        #pragma unroll 8
        for (int k = 0; k < H; ++k) a += hrow[k] * fcw[j*H + k];
        out[b*24 + j] = a;
    }
}

extern "C" void kernel_launch(void* const* d_in, const int* in_sizes, int n_in,
                              void* d_out, int out_size, void* d_ws, size_t ws_size,
                              hipStream_t stream) {
    const float* x   = (const float*)d_in[0];
    const float* Wa  = (const float*)d_in[1];
    const float* Ua  = (const float*)d_in[2];
    const float* ba  = (const float*)d_in[3];
    const float* Va  = (const float*)d_in[4];
    const float* Wih = (const float*)d_in[5];
    const float* Whh = (const float*)d_in[6];
    const float* bih = (const float*)d_in[7];
    const float* bhh = (const float*)d_in[8];
    const float* fcw = (const float*)d_in[9];
    const float* fcb = (const float*)d_in[10];
    float* out = (float*)d_out;
    float* ws  = (float*)d_ws;

    hipLaunchKernelGGL(init_zero, dim3((B*H + 255)/256), dim3(256), 0, stream, ws);
    for (int t = 0; t < S; ++t) {
        hipLaunchKernelGGL(attn_kernel, dim3(B/2), dim3(256), 0, stream,
                           x, Wa, Ua, ba, Va, ws, t);
        hipLaunchKernelGGL(gates_kernel, dim3(16, 16), dim3(256), 0, stream,
                           Wih, Whh, bih, bhh, ws, t);
    }
    hipLaunchKernelGGL(fc_kernel, dim3(B), dim3(256), 0, stream, fcw, fcb, ws, out);
}